// Round 15
// baseline (246.092 us; speedup 1.0000x reference)
//
#include <hip/hip_runtime.h>
#include <stdint.h>

// ---------------------------------------------------------------------------
// CausalSelfAttention: x[4,2048,1024] -> qkv -> flash attn -> proj
// Round 18: V-transpose folded into the QKV GEMM epilogue.  k_tv deleted
// (was 33.5 MB of re-read/re-write HBM traffic + a launch boundary).
// QKV epilogue: cols <2048 -> qkv as before; cols >=2048 -> vt DIRECTLY,
// transposed via an LDS bounce reusing the dead lA buffer (64-col chunks,
// ls[d][t] pad 264 = 16B-aligned reads + 2-way banks; 512-thread coalesced
// 512B-row stores to vt).  qkv's V region never written (flash reads only
// Q/K from qkv).  Launches 5 -> 4.
// Flash (R14 split-wait, measured clean), prep, GEMM K-loop unchanged.
// ---------------------------------------------------------------------------

typedef __attribute__((ext_vector_type(8))) short short8;   // 8 bf16 (4 VGPRs)
typedef __attribute__((ext_vector_type(4))) float floatx4;  // MFMA C/D frag

#define AS1C(p) ((const __attribute__((address_space(1))) void*)(p))
#define AS3(p)  ((__attribute__((address_space(3))) void*)(p))
#define GL16(src, dst) __builtin_amdgcn_global_load_lds(AS1C(src), AS3(dst), 16, 0, 0)
#define BARRIER() do { asm volatile("" ::: "memory"); __builtin_amdgcn_s_barrier(); asm volatile("" ::: "memory"); } while (0)

__device__ __forceinline__ unsigned short f2bf(float f) {
  unsigned int u = __builtin_bit_cast(unsigned int, f);
  u = (u + 0x7fffu + ((u >> 16) & 1u)) >> 16;   // RNE
  return (unsigned short)u;
}
__device__ __forceinline__ unsigned short f2bf_trunc(float f) {
  return (unsigned short)(__builtin_bit_cast(unsigned int, f) >> 16);
}

// ---------------------------------------------------------------------------
// Fused prep: [0,8192) cvt x->bf16; [8192,11264) tw W_attn; [11264,12288) tw
// W_proj.
// ---------------------------------------------------------------------------
__global__ __launch_bounds__(256)
void k_prep(const float* __restrict__ x, unsigned short* __restrict__ xb,
            const float* __restrict__ Wa, unsigned short* __restrict__ WaT,
            const float* __restrict__ Wp, unsigned short* __restrict__ WpT) {
  __shared__ float t[32][33];
  int bid = blockIdx.x;
  int tid = threadIdx.x;
  if (bid < 8192) {
    int i = bid * 256 + tid;           // n4 = 2097152 = 8192*256 exactly
    float4 v = ((const float4*)x)[i];
    ushort4 o;
    o.x = f2bf(v.x); o.y = f2bf(v.y); o.z = f2bf(v.z); o.w = f2bf(v.w);
    ((ushort4*)xb)[i] = o;
    return;
  }
  const float* in; unsigned short* out; int K = 1024, N, n0, k0;
  if (bid < 11264) {                   // W_attn: 96x32 tiles of [1024][3072]
    int b2 = bid - 8192;
    in = Wa; out = WaT; N = 3072;
    n0 = (b2 % 96) * 32; k0 = (b2 / 96) * 32;
  } else {                             // W_proj: 32x32 tiles of [1024][1024]
    int b2 = bid - 11264;
    in = Wp; out = WpT; N = 1024;
    n0 = (b2 % 32) * 32; k0 = (b2 / 32) * 32;
  }
  int tx = tid & 31, ty = tid >> 5;
#pragma unroll
  for (int i = 0; i < 4; i++)
    t[ty + 8 * i][tx] = in[(size_t)(k0 + ty + 8 * i) * N + n0 + tx];
  __syncthreads();
#pragma unroll
  for (int i = 0; i < 4; i++)
    out[(size_t)(n0 + ty + 8 * i) * K + k0 + tx] = f2bf(t[tx][ty + 8 * i]);
}

// ---------------------------------------------------------------------------
// 256x(NF*64)-tile bf16 GEMM, C = A[M,K] @ Bt[N,K]^T + bias.
// A+B double-buffered; one barrier + one vmcnt per K-tile (R8 schedule).
// OUT_F32==0 (QKV): cols <2048 -> Cout (qkv); cols >=2048 -> vt transposed
// via LDS bounce (64-col chunks through the dead lA buffer).
// ---------------------------------------------------------------------------
template <int OUT_F32, int NF>
__global__ __launch_bounds__(512, 2)
void k_gemm8(const unsigned short* __restrict__ A,
             const unsigned short* __restrict__ Bt,
             const float* __restrict__ bias,
             void* __restrict__ Cout,
             unsigned short* __restrict__ vt,
             int M, int N, int K) {
  __shared__ unsigned short lA[2][256 * 64];        // 64 KiB
  __shared__ unsigned short lB[2][NF * 64 * 64];    // 48 (NF=3) / 32 (NF=2) KiB
  int tid = threadIdx.x;
  int lane = tid & 63, wv = tid >> 6;               // 8 waves
  int lc = lane & 15, quad = lane >> 4;
  int sw = lc & 7;

  // T1: XCD-aware block swizzle (nwg % 8 == 0 for both launches)
  unsigned nbx = gridDim.x;
  unsigned nwg = nbx * gridDim.y;
  unsigned flat = blockIdx.y * nbx + blockIdx.x;
  unsigned cpx = nwg >> 3;
  unsigned tile = (flat & 7u) * cpx + (flat >> 3);
  int n0 = (int)(tile % nbx) * (NF * 64);
  int m0 = (int)(tile / nbx) * 256;

  int wm = (wv >> 2) * 128;         // 0,128
  int wn = (wv & 3) * (NF * 16);    // 4 N-waves

  floatx4 acc[8][NF];
#pragma unroll
  for (int i = 0; i < 8; i++)
#pragma unroll
    for (int j = 0; j < NF; j++) acc[i][j] = (floatx4){0.f, 0.f, 0.f, 0.f};

  // staging geometry: one gload issue = 512 thr x 16B = 8 KiB = 64 rows
  int srow = tid >> 3;                          // 0..63
  int scol = ((tid & 7) ^ (srow & 7)) * 8;      // inverse-swizzled source chunk
  const unsigned short* gA = A + (size_t)(m0 + srow) * K + scol;
  const unsigned short* gB = Bt + (size_t)(n0 + srow) * K + scol;

  int NT = K >> 6;

  // prologue: stage K-tile 0 into parity 0; wait; barrier.
#pragma unroll
  for (int i = 0; i < 4; i++)  GL16(gA + (size_t)(i * 64) * K, &lA[0][i * 4096 + wv * 512]);
#pragma unroll
  for (int i = 0; i < NF; i++) GL16(gB + (size_t)(i * 64) * K, &lB[0][i * 4096 + wv * 512]);
  asm volatile("s_waitcnt vmcnt(0)" ::: "memory");
  __builtin_amdgcn_s_barrier();
  asm volatile("" ::: "memory");

  for (int t = 0; t < NT; ++t) {
    const unsigned short* bufA = lA[t & 1];
    const unsigned short* bufB = lB[t & 1];
    bool st = (t + 1) < NT;

    // issue next tile's staging FIRST (full-tile latency cover).
    if (st) {
      unsigned short* nA = lA[(t + 1) & 1];
      unsigned short* nB = lB[(t + 1) & 1];
      int k1 = (t + 1) << 6;
#pragma unroll
      for (int i = 0; i < 4; i++)
        GL16(gA + (size_t)(i * 64) * K + k1, nA + i * 4096 + wv * 512);
#pragma unroll
      for (int i = 0; i < NF; i++)
        GL16(gB + (size_t)(i * 64) * K + k1, nB + i * 4096 + wv * 512);
    }

    // ---- compute tile t: one barrier-free region ----
    short8 af[4][2], bf[NF][2];
#pragma unroll
    for (int n = 0; n < NF; n++)
#pragma unroll
      for (int ks = 0; ks < 2; ks++)
        bf[n][ks] = *(const short8*)(bufB + (wn + n * 16 + lc) * 64 + (((ks * 4 + quad) ^ sw) * 8));
#pragma unroll
    for (int m = 0; m < 4; m++)
#pragma unroll
      for (int ks = 0; ks < 2; ks++)
        af[m][ks] = *(const short8*)(bufA + (wm + m * 16 + lc) * 64 + (((ks * 4 + quad) ^ sw) * 8));
    __builtin_amdgcn_s_setprio(1);
#pragma unroll
    for (int m = 0; m < 4; m++)
#pragma unroll
      for (int n = 0; n < NF; n++)
#pragma unroll
        for (int ks = 0; ks < 2; ks++)
          acc[m][n] = __builtin_amdgcn_mfma_f32_16x16x32_bf16(af[m][ks], bf[n][ks], acc[m][n], 0, 0, 0);
    __builtin_amdgcn_s_setprio(0);
#pragma unroll
    for (int m = 0; m < 4; m++)
#pragma unroll
      for (int ks = 0; ks < 2; ks++)
        af[m][ks] = *(const short8*)(bufA + (wm + (m + 4) * 16 + lc) * 64 + (((ks * 4 + quad) ^ sw) * 8));
    __builtin_amdgcn_s_setprio(1);
#pragma unroll
    for (int m = 0; m < 4; m++)
#pragma unroll
      for (int n = 0; n < NF; n++)
#pragma unroll
        for (int ks = 0; ks < 2; ks++)
          acc[m + 4][n] = __builtin_amdgcn_mfma_f32_16x16x32_bf16(af[m][ks], bf[n][ks], acc[m + 4][n], 0, 0, 0);
    __builtin_amdgcn_s_setprio(0);

    // ---- tile boundary: t+1 landed (issued a full tile ago) + barrier ----
    if (st) {
      asm volatile("s_waitcnt vmcnt(0)" ::: "memory");
      BARRIER();
    }
  }

  // ---- epilogue ----
  float bv[NF];
#pragma unroll
  for (int j = 0; j < NF; j++) bv[j] = bias[n0 + wn + j * 16 + lc];

  if constexpr (OUT_F32) {
    // proj: plain f32 output
#pragma unroll
    for (int i = 0; i < 8; i++)
#pragma unroll
      for (int j = 0; j < NF; j++)
#pragma unroll
        for (int r = 0; r < 4; r++) {
          size_t idx = (size_t)(m0 + wm + i * 16 + quad * 4 + r) * N + (n0 + wn + j * 16 + lc);
          ((float*)Cout)[idx] = acc[i][j][r] + bv[j];
        }
  } else {
    // QKV: cols <2048 -> qkv (bf16); cols >=2048 -> vt transposed via LDS.
#pragma unroll
    for (int i = 0; i < 8; i++)
#pragma unroll
      for (int j = 0; j < NF; j++) {
        int col = n0 + wn + j * 16 + lc;
        if (col < 2048) {
#pragma unroll
          for (int r = 0; r < 4; r++) {
            size_t idx = (size_t)(m0 + wm + i * 16 + quad * 4 + r) * N + col;
            ((unsigned short*)Cout)[idx] = f2bf(acc[i][j][r] + bv[j]);
          }
        }
      }
    int vend = n0 + NF * 64;
    if (vend > 2048) {
      unsigned short* ls = &lA[0][0];       // 64 KiB scratch (K-loop done)
      int bb = m0 >> 11;                    // batch index (2048 rows per b)
      int gt0 = m0 & 2047;                  // time offset within batch
      int c0beg = (n0 < 2048) ? 2048 : n0;  // 64-aligned (all n0 are)
      for (int c0 = c0beg; c0 < vend; c0 += 64) {
        BARRIER();   // lA safe: closes last K-tile reads / prev chunk reads
        // scatter this wave's cols in [c0, c0+64) into ls[d][t]  (pad 264)
#pragma unroll
        for (int j = 0; j < NF; j++) {
          int col = n0 + wn + j * 16 + lc;
          if (col >= c0 && col < c0 + 64) {
            int d = col - c0;
#pragma unroll
            for (int i = 0; i < 8; i++)
#pragma unroll
              for (int r = 0; r < 4; r++) {
                int row = wm + i * 16 + quad * 4 + r;
                ls[d * 264 + row] = f2bf(acc[i][j][r] + bv[j]);
              }
          }
        }
        BARRIER();
        // coalesced store: thread -> (d = tid>>3, 32-t chunk), 4 x 16B
        int d = tid >> 3, ts = (tid & 7) * 32;
        int gd = c0 - 2048 + d;
        size_t vrow = (size_t)(bb * 16 + (gd >> 6)) * 64 + (gd & 63);
#pragma unroll
        for (int k = 0; k < 4; k++) {
          short8 vv = *(const short8*)(ls + d * 264 + ts + k * 8);
          *(short8*)(vt + vrow * 2048 + gt0 + ts + k * 8) = vv;
        }
      }
    }
  }
}

// ---- flash attention: paired q-tiles, XCD-grouped, split-wait schedule ----
#define LP_STRIDE 68   // pad: pf b128 reads land 2-way/bank (free)
__global__ __launch_bounds__(256, 4)
void k_flash(const unsigned short* __restrict__ qkv,
             const unsigned short* __restrict__ vt,
             unsigned short* __restrict__ y) {
  __shared__ unsigned short lK[64 * 64];
  __shared__ unsigned short lVT[64 * 64];
  __shared__ unsigned short lP[4][2][16 * LP_STRIDE];
  int tid = threadIdx.x, lane = tid & 63, wv = tid >> 6;
  int lc = lane & 15, quad = lane >> 4;
  int sw = lc & 7;

  // XCD grouping: each XCD owns 8 bh values with ALL 16 q-pair blocks.
  int raw = blockIdx.y * 16 + blockIdx.x;      // 0..1023
  int bh  = (raw & 7) * 8 + ((raw >> 3) & 7);  // 0..63
  int j   = raw >> 6;                          // 0..15
  int b = bh >> 4, h = bh & 15;
  int qtA = j, qtB = 31 - j;
  int qrA = qtA * 64 + wv * 16;
  int qrB = qtB * 64 + wv * 16;

  short8 qfA[2], qfB[2];
  {
    const unsigned short* qp = qkv + (size_t)(b * 2048 + qrA + lc) * 3072 + h * 64 + quad * 8;
    qfA[0] = *(const short8*)qp;
    qfA[1] = *(const short8*)(qp + 32);
  }
  {
    const unsigned short* qp = qkv + (size_t)(b * 2048 + qrB + lc) * 3072 + h * 64 + quad * 8;
    qfB[0] = *(const short8*)qp;
    qfB[1] = *(const short8*)(qp + 32);
  }

  float rsA[4] = {0.f, 0.f, 0.f, 0.f}, rsB[4] = {0.f, 0.f, 0.f, 0.f};
  floatx4 oA[4], oB[4];
#pragma unroll
  for (int dt = 0; dt < 4; dt++) {
    oA[dt] = (floatx4){0.f, 0.f, 0.f, 0.f};
    oB[dt] = (floatx4){0.f, 0.f, 0.f, 0.f};
  }

  int srow = tid >> 3;
  int scol = ((tid & 7) ^ (srow & 7)) * 8;    // swizzled gather column
  const unsigned short* gK = qkv + (size_t)(b * 2048 + srow) * 3072 + 1024 + h * 64 + scol;
  const unsigned short* gV = vt + (size_t)(bh * 64 + srow) * 2048 + scol;

  const float SC2 = 0.18033688011f;   // (1/sqrt(64)) * log2(e)
  int nt = qtB + 1;

  // prologue: issue K(0) only (V(0) issued at iter top).
#pragma unroll
  for (int c = 0; c < 2; c++)
    GL16(gK + (size_t)(32 * c) * 3072, lK + (32 * c + 8 * wv) * 64);

  for (int kv = 0; kv < nt; kv++) {
    int kv0 = kv * 64;

    // (1) issue V(kv); (2) wait K(kv) only: the 2 newest ops are V(kv).
#pragma unroll
    for (int c = 0; c < 2; c++)
      GL16(gV + (size_t)(32 * c) * 2048 + kv0, lVT + (32 * c + 8 * wv) * 64);
    asm volatile("s_waitcnt vmcnt(2)" ::: "memory");
    BARRIER();   // all waves have K(kv)

    bool withA = (kv <= qtA);

    // ---- (3) S = Q K^T for both q-tiles, sharing K fragments ----
    floatx4 sB[4], sA[4];
    __builtin_amdgcn_s_setprio(1);
#pragma unroll
    for (int n = 0; n < 4; n++) {
      short8 kf0 = *(const short8*)(lK + (n * 16 + lc) * 64 + ((quad ^ sw) * 8));
      short8 kf1 = *(const short8*)(lK + (n * 16 + lc) * 64 + (((4 + quad) ^ sw) * 8));
      floatx4 t = (floatx4){0.f, 0.f, 0.f, 0.f};
      t = __builtin_amdgcn_mfma_f32_16x16x32_bf16(qfB[0], kf0, t, 0, 0, 0);
      t = __builtin_amdgcn_mfma_f32_16x16x32_bf16(qfB[1], kf1, t, 0, 0, 0);
      sB[n] = t;
      if (withA) {
        floatx4 u = (floatx4){0.f, 0.f, 0.f, 0.f};
        u = __builtin_amdgcn_mfma_f32_16x16x32_bf16(qfA[0], kf0, u, 0, 0, 0);
        u = __builtin_amdgcn_mfma_f32_16x16x32_bf16(qfA[1], kf1, u, 0, 0, 0);
        sA[n] = u;
      }
    }
    __builtin_amdgcn_s_setprio(0);

    // ---- softmax numerators (no max subtraction), P -> LDS (trunc pack) ----
    {
      bool diag = (kv == qtB);
#pragma unroll
      for (int n = 0; n < 4; n++)
#pragma unroll
        for (int r = 0; r < 4; r++) {
          float arg = sB[n][r] * SC2;
          if (diag && (kv0 + n * 16 + lc > qrB + quad * 4 + r)) arg = -__builtin_inff();
          float p = __builtin_amdgcn_exp2f(arg);
          rsB[r] += p;
          lP[wv][0][(quad * 4 + r) * LP_STRIDE + n * 16 + lc] = f2bf_trunc(p);
        }
    }
    if (withA) {
      bool diag = (kv == qtA);
#pragma unroll
      for (int n = 0; n < 4; n++)
#pragma unroll
        for (int r = 0; r < 4; r++) {
          float arg = sA[n][r] * SC2;
          if (diag && (kv0 + n * 16 + lc > qrA + quad * 4 + r)) arg = -__builtin_inff();
          float p = __builtin_amdgcn_exp2f(arg);
          rsA[r] += p;
          lP[wv][1][(quad * 4 + r) * LP_STRIDE + n * 16 + lc] = f2bf_trunc(p);
        }
    }

    // (4) V(kv) landed (issued at iter top; latency hidden under QK^T+softmax)
    asm volatile("s_waitcnt vmcnt(0)" ::: "memory");
    BARRIER();

    // (5) issue K(kv+1): legal single-buffered -- every wave's lK reads
    // retired (consumed by MFMAs) before its mid-barrier above.
    if (kv + 1 < nt) {
      int kn0 = kv0 + 64;
#pragma unroll
      for (int c = 0; c < 2; c++)
        GL16(gK + (size_t)(kn0 + 32 * c) * 3072, lK + (32 * c + 8 * wv) * 64);
    }

    // ---- (6) O += P @ V, sharing V fragments ----
    __builtin_amdgcn_s_setprio(1);
#pragma unroll
    for (int s2 = 0; s2 < 2; s2++) {
      short8 pfB = *(const short8*)(&lP[wv][0][0] + lc * LP_STRIDE + s2 * 32 + quad * 8);
      short8 pfA;
      if (withA) pfA = *(const short8*)(&lP[wv][1][0] + lc * LP_STRIDE + s2 * 32 + quad * 8);
#pragma unroll
      for (int dt = 0; dt < 4; dt++) {
        short8 vf = *(const short8*)(lVT + (dt * 16 + lc) * 64 + (((s2 * 4 + quad) ^ sw) * 8));
        oB[dt] = __builtin_amdgcn_mfma_f32_16x16x32_bf16(pfB, vf, oB[dt], 0, 0, 0);
        if (withA) oA[dt] = __builtin_amdgcn_mfma_f32_16x16x32_bf16(pfA, vf, oA[dt], 0, 0, 0);
      }
    }
    __builtin_amdgcn_s_setprio(0);
    BARRIER();   // (7) protect lVT before next iter's V writes
  }

  // ---- epilogue: one row-sum butterfly, normalize, store both tiles ----
#pragma unroll
  for (int off = 1; off < 16; off <<= 1)
#pragma unroll
    for (int r = 0; r < 4; r++) {
      rsA[r] += __shfl_xor(rsA[r], off);
      rsB[r] += __shfl_xor(rsB[r], off);
    }
#pragma unroll
  for (int r = 0; r < 4; r++) {
    float invA = 1.0f / rsA[r];
    float invB = 1.0f / rsB[r];
#pragma unroll
    for (int dt = 0; dt < 4; dt++) {
      size_t ia = (size_t)(b * 2048 + qrA + quad * 4 + r) * 1024 + h * 64 + dt * 16 + lc;
      size_t ib = (size_t)(b * 2048 + qrB + quad * 4 + r) * 1024 + h * 64 + dt * 16 + lc;
      y[ia] = f2bf(oA[dt][r] * invA);
      y[ib] = f2bf(oB[dt][r] * invB);
    }
  }
}

extern "C" void kernel_launch(void* const* d_in, const int* in_sizes, int n_in,
                              void* d_out, int out_size, void* d_ws, size_t ws_size,
                              hipStream_t stream) {
  const float* x      = (const float*)d_in[0];
  const float* W_attn = (const float*)d_in[1];
  const float* b_attn = (const float*)d_in[2];
  const float* W_proj = (const float*)d_in[3];
  const float* b_proj = (const float*)d_in[4];

  char* ws = (char*)d_ws;
  unsigned short* xb     = (unsigned short*)ws;                    // 16.8 MB (reused as y)
  unsigned short* wattnT = (unsigned short*)(ws + 16777216);       // 6.3 MB
  unsigned short* wprojT = (unsigned short*)(ws + 23068672);       // 2.1 MB
  unsigned short* qkv    = (unsigned short*)(ws + 25165824);       // 50.3 MB (V third unused)
  unsigned short* vt     = (unsigned short*)(ws + 75497472);       // 16.8 MB -> total 92.3 MB
  unsigned short* y      = xb;   // xb dead after QKV GEMM

  // fused prep: cvt (8192 blocks) + tw W_attn (3072) + tw W_proj (1024)
  k_prep<<<12288, 256, 0, stream>>>(x, xb, W_attn, wattnT, W_proj, wprojT);
  // QKV GEMM: 256x192 tiles, 16x32 = 512 blocks = 2 exact rounds.
  // Writes qkv (Q,K cols) AND vt (V cols, transposed in-epilogue).
  k_gemm8<0, 3><<<dim3(16, 32), 512, 0, stream>>>(xb, wattnT, b_attn, qkv, vt, 8192, 3072, 1024);
  k_flash<<<dim3(16, 64), 256, 0, stream>>>(qkv, vt, y);
  // proj GEMM: 256x128 tiles, 8x32 = 256 blocks = 1 exact round
  k_gemm8<1, 2><<<dim3(8, 32), 512, 0, stream>>>(y, wprojT, b_proj, d_out, nullptr, 8192, 1024, 1024);
}

// Round 16
// 244.639 us; speedup vs baseline: 1.0059x; 1.0059x over previous
//
#include <hip/hip_runtime.h>
#include <stdint.h>

// ---------------------------------------------------------------------------
// CausalSelfAttention: x[4,2048,1024] -> qkv -> flash attn -> proj
// Round 19: proj GEMM rebuilt as k_gemm4 (128x128 tile, 4 waves, A+B dbuf
// = 64 KiB -> 2 desynced blocks/CU, 512 blocks = 2 rounds).  R0 measured
// proj at 82 us / 208 TF (3x worse than QKV per-FLOP); its 1-round 1-blk/CU
// geometry exposes every per-tile drain.  Flash proved co-resident desynced
// blocks hide these waits.  Intensity kept at 2.0 MFMA/b128 (R6 level) and
// no mid-tile vmcnt(0) -- the two R7 confounds removed.
// QKV (R15 fused-V epilogue), flash (split-wait), prep unchanged.
// ---------------------------------------------------------------------------

typedef __attribute__((ext_vector_type(8))) short short8;   // 8 bf16 (4 VGPRs)
typedef __attribute__((ext_vector_type(4))) float floatx4;  // MFMA C/D frag

#define AS1C(p) ((const __attribute__((address_space(1))) void*)(p))
#define AS3(p)  ((__attribute__((address_space(3))) void*)(p))
#define GL16(src, dst) __builtin_amdgcn_global_load_lds(AS1C(src), AS3(dst), 16, 0, 0)
#define BARRIER() do { asm volatile("" ::: "memory"); __builtin_amdgcn_s_barrier(); asm volatile("" ::: "memory"); } while (0)

__device__ __forceinline__ unsigned short f2bf(float f) {
  unsigned int u = __builtin_bit_cast(unsigned int, f);
  u = (u + 0x7fffu + ((u >> 16) & 1u)) >> 16;   // RNE
  return (unsigned short)u;
}
__device__ __forceinline__ unsigned short f2bf_trunc(float f) {
  return (unsigned short)(__builtin_bit_cast(unsigned int, f) >> 16);
}

// ---------------------------------------------------------------------------
// Fused prep: [0,8192) cvt x->bf16; [8192,11264) tw W_attn; [11264,12288) tw
// W_proj.
// ---------------------------------------------------------------------------
__global__ __launch_bounds__(256)
void k_prep(const float* __restrict__ x, unsigned short* __restrict__ xb,
            const float* __restrict__ Wa, unsigned short* __restrict__ WaT,
            const float* __restrict__ Wp, unsigned short* __restrict__ WpT) {
  __shared__ float t[32][33];
  int bid = blockIdx.x;
  int tid = threadIdx.x;
  if (bid < 8192) {
    int i = bid * 256 + tid;           // n4 = 2097152 = 8192*256 exactly
    float4 v = ((const float4*)x)[i];
    ushort4 o;
    o.x = f2bf(v.x); o.y = f2bf(v.y); o.z = f2bf(v.z); o.w = f2bf(v.w);
    ((ushort4*)xb)[i] = o;
    return;
  }
  const float* in; unsigned short* out; int K = 1024, N, n0, k0;
  if (bid < 11264) {                   // W_attn: 96x32 tiles of [1024][3072]
    int b2 = bid - 8192;
    in = Wa; out = WaT; N = 3072;
    n0 = (b2 % 96) * 32; k0 = (b2 / 96) * 32;
  } else {                             // W_proj: 32x32 tiles of [1024][1024]
    int b2 = bid - 11264;
    in = Wp; out = WpT; N = 1024;
    n0 = (b2 % 32) * 32; k0 = (b2 / 32) * 32;
  }
  int tx = tid & 31, ty = tid >> 5;
#pragma unroll
  for (int i = 0; i < 4; i++)
    t[ty + 8 * i][tx] = in[(size_t)(k0 + ty + 8 * i) * N + n0 + tx];
  __syncthreads();
#pragma unroll
  for (int i = 0; i < 4; i++)
    out[(size_t)(n0 + ty + 8 * i) * K + k0 + tx] = f2bf(t[tx][ty + 8 * i]);
}

// ---------------------------------------------------------------------------
// QKV GEMM: 256x192 tile (NF=3), 8 waves, A+B dbuf, 1 barrier/K-tile.
// Epilogue: cols <2048 -> qkv; cols >=2048 -> vt transposed via LDS bounce.
// ---------------------------------------------------------------------------
template <int OUT_F32, int NF>
__global__ __launch_bounds__(512, 2)
void k_gemm8(const unsigned short* __restrict__ A,
             const unsigned short* __restrict__ Bt,
             const float* __restrict__ bias,
             void* __restrict__ Cout,
             unsigned short* __restrict__ vt,
             int M, int N, int K) {
  __shared__ unsigned short lA[2][256 * 64];        // 64 KiB
  __shared__ unsigned short lB[2][NF * 64 * 64];    // 48 KiB (NF=3)
  int tid = threadIdx.x;
  int lane = tid & 63, wv = tid >> 6;               // 8 waves
  int lc = lane & 15, quad = lane >> 4;
  int sw = lc & 7;

  // T1: XCD-aware block swizzle (nwg % 8 == 0)
  unsigned nbx = gridDim.x;
  unsigned nwg = nbx * gridDim.y;
  unsigned flat = blockIdx.y * nbx + blockIdx.x;
  unsigned cpx = nwg >> 3;
  unsigned tile = (flat & 7u) * cpx + (flat >> 3);
  int n0 = (int)(tile % nbx) * (NF * 64);
  int m0 = (int)(tile / nbx) * 256;

  int wm = (wv >> 2) * 128;         // 0,128
  int wn = (wv & 3) * (NF * 16);    // 4 N-waves

  floatx4 acc[8][NF];
#pragma unroll
  for (int i = 0; i < 8; i++)
#pragma unroll
    for (int j = 0; j < NF; j++) acc[i][j] = (floatx4){0.f, 0.f, 0.f, 0.f};

  // staging geometry: one gload issue = 512 thr x 16B = 8 KiB = 64 rows
  int srow = tid >> 3;                          // 0..63
  int scol = ((tid & 7) ^ (srow & 7)) * 8;      // inverse-swizzled source chunk
  const unsigned short* gA = A + (size_t)(m0 + srow) * K + scol;
  const unsigned short* gB = Bt + (size_t)(n0 + srow) * K + scol;

  int NT = K >> 6;

  // prologue: stage K-tile 0 into parity 0; wait; barrier.
#pragma unroll
  for (int i = 0; i < 4; i++)  GL16(gA + (size_t)(i * 64) * K, &lA[0][i * 4096 + wv * 512]);
#pragma unroll
  for (int i = 0; i < NF; i++) GL16(gB + (size_t)(i * 64) * K, &lB[0][i * 4096 + wv * 512]);
  asm volatile("s_waitcnt vmcnt(0)" ::: "memory");
  __builtin_amdgcn_s_barrier();
  asm volatile("" ::: "memory");

  for (int t = 0; t < NT; ++t) {
    const unsigned short* bufA = lA[t & 1];
    const unsigned short* bufB = lB[t & 1];
    bool st = (t + 1) < NT;

    // issue next tile's staging FIRST (full-tile latency cover).
    if (st) {
      unsigned short* nA = lA[(t + 1) & 1];
      unsigned short* nB = lB[(t + 1) & 1];
      int k1 = (t + 1) << 6;
#pragma unroll
      for (int i = 0; i < 4; i++)
        GL16(gA + (size_t)(i * 64) * K + k1, nA + i * 4096 + wv * 512);
#pragma unroll
      for (int i = 0; i < NF; i++)
        GL16(gB + (size_t)(i * 64) * K + k1, nB + i * 4096 + wv * 512);
    }

    // ---- compute tile t: one barrier-free region ----
    short8 af[4][2], bf[NF][2];
#pragma unroll
    for (int n = 0; n < NF; n++)
#pragma unroll
      for (int ks = 0; ks < 2; ks++)
        bf[n][ks] = *(const short8*)(bufB + (wn + n * 16 + lc) * 64 + (((ks * 4 + quad) ^ sw) * 8));
#pragma unroll
    for (int m = 0; m < 4; m++)
#pragma unroll
      for (int ks = 0; ks < 2; ks++)
        af[m][ks] = *(const short8*)(bufA + (wm + m * 16 + lc) * 64 + (((ks * 4 + quad) ^ sw) * 8));
    __builtin_amdgcn_s_setprio(1);
#pragma unroll
    for (int m = 0; m < 4; m++)
#pragma unroll
      for (int n = 0; n < NF; n++)
#pragma unroll
        for (int ks = 0; ks < 2; ks++)
          acc[m][n] = __builtin_amdgcn_mfma_f32_16x16x32_bf16(af[m][ks], bf[n][ks], acc[m][n], 0, 0, 0);
    __builtin_amdgcn_s_setprio(0);
#pragma unroll
    for (int m = 0; m < 4; m++)
#pragma unroll
      for (int ks = 0; ks < 2; ks++)
        af[m][ks] = *(const short8*)(bufA + (wm + (m + 4) * 16 + lc) * 64 + (((ks * 4 + quad) ^ sw) * 8));
    __builtin_amdgcn_s_setprio(1);
#pragma unroll
    for (int m = 0; m < 4; m++)
#pragma unroll
      for (int n = 0; n < NF; n++)
#pragma unroll
        for (int ks = 0; ks < 2; ks++)
          acc[m + 4][n] = __builtin_amdgcn_mfma_f32_16x16x32_bf16(af[m][ks], bf[n][ks], acc[m + 4][n], 0, 0, 0);
    __builtin_amdgcn_s_setprio(0);

    // ---- tile boundary: t+1 landed (issued a full tile ago) + barrier ----
    if (st) {
      asm volatile("s_waitcnt vmcnt(0)" ::: "memory");
      BARRIER();
    }
  }

  // ---- epilogue ----
  float bv[NF];
#pragma unroll
  for (int j = 0; j < NF; j++) bv[j] = bias[n0 + wn + j * 16 + lc];

  if constexpr (OUT_F32) {
#pragma unroll
    for (int i = 0; i < 8; i++)
#pragma unroll
      for (int j = 0; j < NF; j++)
#pragma unroll
        for (int r = 0; r < 4; r++) {
          size_t idx = (size_t)(m0 + wm + i * 16 + quad * 4 + r) * N + (n0 + wn + j * 16 + lc);
          ((float*)Cout)[idx] = acc[i][j][r] + bv[j];
        }
  } else {
    // QKV: cols <2048 -> qkv (bf16); cols >=2048 -> vt transposed via LDS.
#pragma unroll
    for (int i = 0; i < 8; i++)
#pragma unroll
      for (int j = 0; j < NF; j++) {
        int col = n0 + wn + j * 16 + lc;
        if (col < 2048) {
#pragma unroll
          for (int r = 0; r < 4; r++) {
            size_t idx = (size_t)(m0 + wm + i * 16 + quad * 4 + r) * N + col;
            ((unsigned short*)Cout)[idx] = f2bf(acc[i][j][r] + bv[j]);
          }
        }
      }
    int vend = n0 + NF * 64;
    if (vend > 2048) {
      unsigned short* ls = &lA[0][0];       // 64 KiB scratch (K-loop done)
      int bb = m0 >> 11;                    // batch index (2048 rows per b)
      int gt0 = m0 & 2047;                  // time offset within batch
      int c0beg = (n0 < 2048) ? 2048 : n0;  // 64-aligned
      for (int c0 = c0beg; c0 < vend; c0 += 64) {
        BARRIER();   // lA safe: closes last K-tile / prev chunk reads
#pragma unroll
        for (int j = 0; j < NF; j++) {
          int col = n0 + wn + j * 16 + lc;
          if (col >= c0 && col < c0 + 64) {
            int d = col - c0;
#pragma unroll
            for (int i = 0; i < 8; i++)
#pragma unroll
              for (int r = 0; r < 4; r++) {
                int row = wm + i * 16 + quad * 4 + r;
                ls[d * 264 + row] = f2bf(acc[i][j][r] + bv[j]);
              }
          }
        }
        BARRIER();
        int d = tid >> 3, ts = (tid & 7) * 32;
        int gd = c0 - 2048 + d;
        size_t vrow = (size_t)(bb * 16 + (gd >> 6)) * 64 + (gd & 63);
#pragma unroll
        for (int k = 0; k < 4; k++) {
          short8 vv = *(const short8*)(ls + d * 264 + ts + k * 8);
          *(short8*)(vt + vrow * 2048 + gt0 + ts + k * 8) = vv;
        }
      }
    }
  }
}

// ---------------------------------------------------------------------------
// proj GEMM: 128x128 tile, 4 waves (per-wave 64x64, acc[4][4]), A+B dbuf
// (64 KiB -> 2 desynced blocks/CU), 1 barrier/K-tile.  Grid 8x64 = 512
// blocks = 2 rounds at 2 blk/CU.  C = A[M,K] @ Bt[N,K]^T + bias, f32 out.
// ---------------------------------------------------------------------------
__global__ __launch_bounds__(256)
void k_gemm4(const unsigned short* __restrict__ A,
             const unsigned short* __restrict__ Bt,
             const float* __restrict__ bias,
             float* __restrict__ C, int M, int N, int K) {
  __shared__ unsigned short lA[2][128 * 64];   // 16 KiB each
  __shared__ unsigned short lB[2][128 * 64];   // -> 64 KiB total
  int tid = threadIdx.x;
  int lane = tid & 63, wv = tid >> 6;          // 4 waves
  int lc = lane & 15, quad = lane >> 4;
  int sw = lc & 7;

  // T1: XCD-aware block swizzle (nwg = 512, % 8 == 0)
  unsigned nbx = gridDim.x;
  unsigned nwg = nbx * gridDim.y;
  unsigned flat = blockIdx.y * nbx + blockIdx.x;
  unsigned cpx = nwg >> 3;
  unsigned tile = (flat & 7u) * cpx + (flat >> 3);
  int n0 = (int)(tile % nbx) * 128;
  int m0 = (int)(tile / nbx) * 128;

  int wm = (wv >> 1) * 64;   // 0,64
  int wn = (wv & 1) * 64;    // 0,64

  floatx4 acc[4][4];
#pragma unroll
  for (int i = 0; i < 4; i++)
#pragma unroll
    for (int j = 0; j < 4; j++) acc[i][j] = (floatx4){0.f, 0.f, 0.f, 0.f};

  // staging: one gload issue = 256 thr x 16B = 4 KiB = 32 rows
  int srow = tid >> 3;                          // 0..31
  int scol = ((tid & 7) ^ (srow & 7)) * 8;      // inverse-swizzled source chunk
  const unsigned short* gA = A + (size_t)(m0 + srow) * K + scol;
  const unsigned short* gB = Bt + (size_t)(n0 + srow) * K + scol;

  int NT = K >> 6;

  // prologue: stage tile 0 into parity 0 (4+4 gloads); wait; barrier.
#pragma unroll
  for (int i = 0; i < 4; i++) GL16(gA + (size_t)(i * 32) * K, &lA[0][i * 2048 + wv * 512]);
#pragma unroll
  for (int i = 0; i < 4; i++) GL16(gB + (size_t)(i * 32) * K, &lB[0][i * 2048 + wv * 512]);
  asm volatile("s_waitcnt vmcnt(0)" ::: "memory");
  __builtin_amdgcn_s_barrier();
  asm volatile("" ::: "memory");

  for (int t = 0; t < NT; ++t) {
    const unsigned short* bufA = lA[t & 1];
    const unsigned short* bufB = lB[t & 1];
    bool st = (t + 1) < NT;

    if (st) {
      unsigned short* nA = lA[(t + 1) & 1];
      unsigned short* nB = lB[(t + 1) & 1];
      int k1 = (t + 1) << 6;
#pragma unroll
      for (int i = 0; i < 4; i++)
        GL16(gA + (size_t)(i * 32) * K + k1, nA + i * 2048 + wv * 512);
#pragma unroll
      for (int i = 0; i < 4; i++)
        GL16(gB + (size_t)(i * 32) * K + k1, nB + i * 2048 + wv * 512);
    }

    short8 af[4][2], bf[4][2];
#pragma unroll
    for (int n = 0; n < 4; n++)
#pragma unroll
      for (int ks = 0; ks < 2; ks++)
        bf[n][ks] = *(const short8*)(bufB + (wn + n * 16 + lc) * 64 + (((ks * 4 + quad) ^ sw) * 8));
#pragma unroll
    for (int m = 0; m < 4; m++)
#pragma unroll
      for (int ks = 0; ks < 2; ks++)
        af[m][ks] = *(const short8*)(bufA + (wm + m * 16 + lc) * 64 + (((ks * 4 + quad) ^ sw) * 8));
    __builtin_amdgcn_s_setprio(1);
#pragma unroll
    for (int m = 0; m < 4; m++)
#pragma unroll
      for (int n = 0; n < 4; n++)
#pragma unroll
        for (int ks = 0; ks < 2; ks++)
          acc[m][n] = __builtin_amdgcn_mfma_f32_16x16x32_bf16(af[m][ks], bf[n][ks], acc[m][n], 0, 0, 0);
    __builtin_amdgcn_s_setprio(0);

    if (st) {
      asm volatile("s_waitcnt vmcnt(0)" ::: "memory");
      BARRIER();
    }
  }

  float bv[4];
#pragma unroll
  for (int j = 0; j < 4; j++) bv[j] = bias[n0 + wn + j * 16 + lc];
#pragma unroll
  for (int i = 0; i < 4; i++)
#pragma unroll
    for (int j = 0; j < 4; j++)
#pragma unroll
      for (int r = 0; r < 4; r++) {
        size_t idx = (size_t)(m0 + wm + i * 16 + quad * 4 + r) * N + (n0 + wn + j * 16 + lc);
        C[idx] = acc[i][j][r] + bv[j];
      }
}

// ---- flash attention: paired q-tiles, XCD-grouped, split-wait schedule ----
#define LP_STRIDE 68   // pad: pf b128 reads land 2-way/bank (free)
__global__ __launch_bounds__(256, 4)
void k_flash(const unsigned short* __restrict__ qkv,
             const unsigned short* __restrict__ vt,
             unsigned short* __restrict__ y) {
  __shared__ unsigned short lK[64 * 64];
  __shared__ unsigned short lVT[64 * 64];
  __shared__ unsigned short lP[4][2][16 * LP_STRIDE];
  int tid = threadIdx.x, lane = tid & 63, wv = tid >> 6;
  int lc = lane & 15, quad = lane >> 4;
  int sw = lc & 7;

  // XCD grouping: each XCD owns 8 bh values with ALL 16 q-pair blocks.
  int raw = blockIdx.y * 16 + blockIdx.x;      // 0..1023
  int bh  = (raw & 7) * 8 + ((raw >> 3) & 7);  // 0..63
  int j   = raw >> 6;                          // 0..15
  int b = bh >> 4, h = bh & 15;
  int qtA = j, qtB = 31 - j;
  int qrA = qtA * 64 + wv * 16;
  int qrB = qtB * 64 + wv * 16;

  short8 qfA[2], qfB[2];
  {
    const unsigned short* qp = qkv + (size_t)(b * 2048 + qrA + lc) * 3072 + h * 64 + quad * 8;
    qfA[0] = *(const short8*)qp;
    qfA[1] = *(const short8*)(qp + 32);
  }
  {
    const unsigned short* qp = qkv + (size_t)(b * 2048 + qrB + lc) * 3072 + h * 64 + quad * 8;
    qfB[0] = *(const short8*)qp;
    qfB[1] = *(const short8*)(qp + 32);
  }

  float rsA[4] = {0.f, 0.f, 0.f, 0.f}, rsB[4] = {0.f, 0.f, 0.f, 0.f};
  floatx4 oA[4], oB[4];
#pragma unroll
  for (int dt = 0; dt < 4; dt++) {
    oA[dt] = (floatx4){0.f, 0.f, 0.f, 0.f};
    oB[dt] = (floatx4){0.f, 0.f, 0.f, 0.f};
  }

  int srow = tid >> 3;
  int scol = ((tid & 7) ^ (srow & 7)) * 8;    // swizzled gather column
  const unsigned short* gK = qkv + (size_t)(b * 2048 + srow) * 3072 + 1024 + h * 64 + scol;
  const unsigned short* gV = vt + (size_t)(bh * 64 + srow) * 2048 + scol;

  const float SC2 = 0.18033688011f;   // (1/sqrt(64)) * log2(e)
  int nt = qtB + 1;

  // prologue: issue K(0) only (V(0) issued at iter top).
#pragma unroll
  for (int c = 0; c < 2; c++)
    GL16(gK + (size_t)(32 * c) * 3072, lK + (32 * c + 8 * wv) * 64);

  for (int kv = 0; kv < nt; kv++) {
    int kv0 = kv * 64;

    // (1) issue V(kv); (2) wait K(kv) only: the 2 newest ops are V(kv).
#pragma unroll
    for (int c = 0; c < 2; c++)
      GL16(gV + (size_t)(32 * c) * 2048 + kv0, lVT + (32 * c + 8 * wv) * 64);
    asm volatile("s_waitcnt vmcnt(2)" ::: "memory");
    BARRIER();   // all waves have K(kv)

    bool withA = (kv <= qtA);

    // ---- (3) S = Q K^T for both q-tiles, sharing K fragments ----
    floatx4 sB[4], sA[4];
    __builtin_amdgcn_s_setprio(1);
#pragma unroll
    for (int n = 0; n < 4; n++) {
      short8 kf0 = *(const short8*)(lK + (n * 16 + lc) * 64 + ((quad ^ sw) * 8));
      short8 kf1 = *(const short8*)(lK + (n * 16 + lc) * 64 + (((4 + quad) ^ sw) * 8));
      floatx4 t = (floatx4){0.f, 0.f, 0.f, 0.f};
      t = __builtin_amdgcn_mfma_f32_16x16x32_bf16(qfB[0], kf0, t, 0, 0, 0);
      t = __builtin_amdgcn_mfma_f32_16x16x32_bf16(qfB[1], kf1, t, 0, 0, 0);
      sB[n] = t;
      if (withA) {
        floatx4 u = (floatx4){0.f, 0.f, 0.f, 0.f};
        u = __builtin_amdgcn_mfma_f32_16x16x32_bf16(qfA[0], kf0, u, 0, 0, 0);
        u = __builtin_amdgcn_mfma_f32_16x16x32_bf16(qfA[1], kf1, u, 0, 0, 0);
        sA[n] = u;
      }
    }
    __builtin_amdgcn_s_setprio(0);

    // ---- softmax numerators (no max subtraction), P -> LDS (trunc pack) ----
    {
      bool diag = (kv == qtB);
#pragma unroll
      for (int n = 0; n < 4; n++)
#pragma unroll
        for (int r = 0; r < 4; r++) {
          float arg = sB[n][r] * SC2;
          if (diag && (kv0 + n * 16 + lc > qrB + quad * 4 + r)) arg = -__builtin_inff();
          float p = __builtin_amdgcn_exp2f(arg);
          rsB[r] += p;
          lP[wv][0][(quad * 4 + r) * LP_STRIDE + n * 16 + lc] = f2bf_trunc(p);
        }
    }
    if (withA) {
      bool diag = (kv == qtA);
#pragma unroll
      for (int n = 0; n < 4; n++)
#pragma unroll
        for (int r = 0; r < 4; r++) {
          float arg = sA[n][r] * SC2;
          if (diag && (kv0 + n * 16 + lc > qrA + quad * 4 + r)) arg = -__builtin_inff();
          float p = __builtin_amdgcn_exp2f(arg);
          rsA[r] += p;
          lP[wv][1][(quad * 4 + r) * LP_STRIDE + n * 16 + lc] = f2bf_trunc(p);
        }
    }

    // (4) V(kv) landed (issued at iter top; latency hidden under QK^T+softmax)
    asm volatile("s_waitcnt vmcnt(0)" ::: "memory");
    BARRIER();

    // (5) issue K(kv+1): legal single-buffered -- every wave's lK reads
    // retired (consumed by MFMAs) before its mid-barrier above.
    if (kv + 1 < nt) {
      int kn0 = kv0 + 64;
#pragma unroll
      for (int c = 0; c < 2; c++)
        GL16(gK + (size_t)(kn0 + 32 * c) * 3072, lK + (32 * c + 8 * wv) * 64);
    }

    // ---- (6) O += P @ V, sharing V fragments ----
    __builtin_amdgcn_s_setprio(1);
#pragma unroll
    for (int s2 = 0; s2 < 2; s2++) {
      short8 pfB = *(const short8*)(&lP[wv][0][0] + lc * LP_STRIDE + s2 * 32 + quad * 8);
      short8 pfA;
      if (withA) pfA = *(const short8*)(&lP[wv][1][0] + lc * LP_STRIDE + s2 * 32 + quad * 8);
#pragma unroll
      for (int dt = 0; dt < 4; dt++) {
        short8 vf = *(const short8*)(lVT + (dt * 16 + lc) * 64 + (((s2 * 4 + quad) ^ sw) * 8));
        oB[dt] = __builtin_amdgcn_mfma_f32_16x16x32_bf16(pfB, vf, oB[dt], 0, 0, 0);
        if (withA) oA[dt] = __builtin_amdgcn_mfma_f32_16x16x32_bf16(pfA, vf, oA[dt], 0, 0, 0);
      }
    }
    __builtin_amdgcn_s_setprio(0);
    BARRIER();   // (7) protect lVT before next iter's V writes
  }

  // ---- epilogue: one row-sum butterfly, normalize, store both tiles ----
#pragma unroll
  for (int off = 1; off < 16; off <<= 1)
#pragma unroll
    for (int r = 0; r < 4; r++) {
      rsA[r] += __shfl_xor(rsA[r], off);
      rsB[r] += __shfl_xor(rsB[r], off);
    }
#pragma unroll
  for (int r = 0; r < 4; r++) {
    float invA = 1.0f / rsA[r];
    float invB = 1.0f / rsB[r];
#pragma unroll
    for (int dt = 0; dt < 4; dt++) {
      size_t ia = (size_t)(b * 2048 + qrA + quad * 4 + r) * 1024 + h * 64 + dt * 16 + lc;
      size_t ib = (size_t)(b * 2048 + qrB + quad * 4 + r) * 1024 + h * 64 + dt * 16 + lc;
      y[ia] = f2bf(oA[dt][r] * invA);
      y[ib] = f2bf(oB[dt][r] * invB);
    }
  }
}

extern "C" void kernel_launch(void* const* d_in, const int* in_sizes, int n_in,
                              void* d_out, int out_size, void* d_ws, size_t ws_size,
                              hipStream_t stream) {
  const float* x      = (const float*)d_in[0];
  const float* W_attn = (const float*)d_in[1];
  const float* b_attn = (const float*)d_in[2];
  const float* W_proj = (const float*)d_in[3];
  const float* b_proj = (const float*)d_in[4];

  char* ws = (char*)d_ws;
  unsigned short* xb     = (unsigned short*)ws;                    // 16.8 MB (reused as y)
  unsigned short* wattnT = (unsigned short*)(ws + 16777216);       // 6.3 MB
  unsigned short* wprojT = (unsigned short*)(ws + 23068672);       // 2.1 MB
  unsigned short* qkv    = (unsigned short*)(ws + 25165824);       // 50.3 MB (V third unused)
  unsigned short* vt     = (unsigned short*)(ws + 75497472);       // 16.8 MB -> total 92.3 MB
  unsigned short* y      = xb;   // xb dead after QKV GEMM

  // fused prep: cvt (8192 blocks) + tw W_attn (3072) + tw W_proj (1024)
  k_prep<<<12288, 256, 0, stream>>>(x, xb, W_attn, wattnT, W_proj, wprojT);
  // QKV GEMM: 256x192 tiles, 16x32 = 512 blocks = 2 exact rounds.
  // Writes qkv (Q,K cols) AND vt (V cols, transposed in-epilogue).
  k_gemm8<0, 3><<<dim3(16, 32), 512, 0, stream>>>(xb, wattnT, b_attn, qkv, vt, 8192, 3072, 1024);
  k_flash<<<dim3(16, 64), 256, 0, stream>>>(qkv, vt, y);
  // proj GEMM: 128x128 tiles, 8x64 = 512 blocks, 2 desynced blocks/CU
  k_gemm4<<<dim3(8, 64), 256, 0, stream>>>(y, wprojT, b_proj, (float*)d_out, 8192, 1024, 1024);
}